// Round 1
// baseline (1396.222 us; speedup 1.0000x reference)
//
#include <hip/hip_runtime.h>
#include <math.h>

#define NS 0.2f  // leaky_relu negative slope

__device__ __forceinline__ float lrelu(float x) { return x > 0.f ? x : NS * x; }

// float atomic max via ordered-int trick (valid for all finite floats & ±inf)
__device__ __forceinline__ void atomicMaxF(float* a, float v) {
    if (v >= 0.f) atomicMax((int*)a, __float_as_int(v));
    else          atomicMin((unsigned int*)a, __float_as_uint(v));
}

// H = X @ W  (N x 128 -> N x 32), plus per-node scores s_src = H@a_s, s_dst = H@a_d
__global__ __launch_bounds__(256) void k_feat1(
    const float* __restrict__ X, const float* __restrict__ W,
    const float* __restrict__ a_s, const float* __restrict__ a_d,
    float* __restrict__ H, float* __restrict__ Ss, float* __restrict__ Sd, int n)
{
    __shared__ float Wl[128 * 32];
    __shared__ float Xl[8 * 128];
    const int tid = threadIdx.x;
    for (int i = tid; i < 128 * 32; i += 256) Wl[i] = W[i];

    const int row0 = blockIdx.x * 8;
    {   // 8 rows x 128 cols = 1024 floats, 256 threads x float4
        int idx = tid * 4;
        int r = idx >> 7, c = idx & 127;
        if (row0 + r < n)
            *reinterpret_cast<float4*>(&Xl[idx]) =
                *reinterpret_cast<const float4*>(&X[(size_t)(row0 + r) * 128 + c]);
    }
    __syncthreads();

    const int r = tid >> 5, c = tid & 31;
    const int row = row0 + r;
    if (row >= n) return;

    float acc = 0.f;
#pragma unroll
    for (int k = 0; k < 128; ++k) acc += Xl[r * 128 + k] * Wl[k * 32 + c];
    H[(size_t)row * 32 + c] = acc;

    float vs = acc * a_s[c];
    float vd = acc * a_d[c];
#pragma unroll
    for (int o = 16; o; o >>= 1) { vs += __shfl_xor(vs, o, 32); vd += __shfl_xor(vd, o, 32); }
    if (c == 0) { Ss[row] = vs; Sd[row] = vd; }
}

// G = relu(In + bias); H = G @ W (32x32); plus scores
__global__ __launch_bounds__(256) void k_feat2(
    const float* __restrict__ In, const float* __restrict__ W,
    const float* __restrict__ bias,
    const float* __restrict__ a_s, const float* __restrict__ a_d,
    float* __restrict__ H, float* __restrict__ Ss, float* __restrict__ Sd, int n)
{
    __shared__ float Wl[32 * 32];
    __shared__ float Xl[8 * 32];
    const int tid = threadIdx.x;
    for (int i = tid; i < 1024; i += 256) Wl[i] = W[i];

    const int r = tid >> 5, c = tid & 31;
    const int row = blockIdx.x * 8 + r;
    if (row < n) Xl[tid] = fmaxf(In[(size_t)row * 32 + c] + bias[c], 0.f);
    __syncthreads();
    if (row >= n) return;

    float acc = 0.f;
#pragma unroll
    for (int k = 0; k < 32; ++k) acc += Xl[r * 32 + k] * Wl[k * 32 + c];
    H[(size_t)row * 32 + c] = acc;

    float vs = acc * a_s[c];
    float vd = acc * a_d[c];
#pragma unroll
    for (int o = 16; o; o >>= 1) { vs += __shfl_xor(vs, o, 32); vd += __shfl_xor(vd, o, 32); }
    if (c == 0) { Ss[row] = vs; Sd[row] = vd; }
}

// Out = sigmoid( relu(In + b_prev) @ Wc + bc )
__global__ __launch_bounds__(256) void k_cls(
    const float* __restrict__ In, const float* __restrict__ W,
    const float* __restrict__ b_prev, const float* __restrict__ bc,
    float* __restrict__ Out, int n)
{
    __shared__ float Wl[32 * 32];
    __shared__ float Xl[8 * 32];
    const int tid = threadIdx.x;
    for (int i = tid; i < 1024; i += 256) Wl[i] = W[i];

    const int r = tid >> 5, c = tid & 31;
    const int row = blockIdx.x * 8 + r;
    if (row < n) Xl[tid] = fmaxf(In[(size_t)row * 32 + c] + b_prev[c], 0.f);
    __syncthreads();
    if (row >= n) return;

    float acc = bc[c];
#pragma unroll
    for (int k = 0; k < 32; ++k) acc += Xl[r * 32 + k] * Wl[k * 32 + c];
    Out[(size_t)row * 32 + c] = 1.f / (1.f + __expf(-acc));
}

// init m = -inf, z = 0, agg = 0   (launched with >= n*32 threads)
__global__ void k_init(float* __restrict__ m, float* __restrict__ z,
                       float* __restrict__ agg, int n)
{
    int i = blockIdx.x * blockDim.x + threadIdx.x;
    if (i < n * 32) agg[i] = 0.f;
    if (i < n) { m[i] = __int_as_float(0xff800000u); z[i] = 0.f; }
}

// pass A: segment max of e over dst
__global__ __launch_bounds__(256) void k_edge_max(
    const int* __restrict__ esrc, const int* __restrict__ edst, int E, int n,
    const float* __restrict__ Ss, const float* __restrict__ Sd, float* __restrict__ m)
{
    int e = blockIdx.x * 256 + threadIdx.x;
    if (e >= E + n) return;
    int s, d;
    if (e < E) { s = esrc[e]; d = edst[e]; } else { s = d = e - E; }
    atomicMaxF(&m[d], lrelu(Ss[s] + Sd[d]));
}

// pass B: z[dst] += exp(e - m[dst])
__global__ __launch_bounds__(256) void k_edge_sum(
    const int* __restrict__ esrc, const int* __restrict__ edst, int E, int n,
    const float* __restrict__ Ss, const float* __restrict__ Sd,
    const float* __restrict__ m, float* __restrict__ z)
{
    int e = blockIdx.x * 256 + threadIdx.x;
    if (e >= E + n) return;
    int s, d;
    if (e < E) { s = esrc[e]; d = edst[e]; } else { s = d = e - E; }
    float ev = lrelu(Ss[s] + Sd[d]);
    atomicAdd(&z[d], __expf(ev - m[d]));
}

// pass C: agg[dst] += alpha * H[src]   (one 32-lane group per edge)
__global__ __launch_bounds__(256) void k_edge_agg(
    const int* __restrict__ esrc, const int* __restrict__ edst, int E, int n,
    const float* __restrict__ Ss, const float* __restrict__ Sd,
    const float* __restrict__ m, const float* __restrict__ z,
    const float* __restrict__ H, float* __restrict__ agg)
{
    int g = blockIdx.x * 8 + (threadIdx.x >> 5);
    int lane = threadIdx.x & 31;
    if (g >= E + n) return;
    int s, d;
    if (g < E) { s = esrc[g]; d = edst[g]; } else { s = d = g - E; }
    float ev = lrelu(Ss[s] + Sd[d]);
    float alpha = __expf(ev - m[d]) / (z[d] + 1e-16f);
    atomicAdd(&agg[(size_t)d * 32 + lane], alpha * H[(size_t)s * 32 + lane]);
}

extern "C" void kernel_launch(void* const* d_in, const int* in_sizes, int n_in,
                              void* d_out, int out_size, void* d_ws, size_t ws_size,
                              hipStream_t stream)
{
    const float* x   = (const float*)d_in[0];
    const int*   ei  = (const int*)d_in[1];
    const float* W1  = (const float*)d_in[2];
    const float* as1 = (const float*)d_in[3];
    const float* ad1 = (const float*)d_in[4];
    const float* b1  = (const float*)d_in[5];
    const float* W2  = (const float*)d_in[6];
    const float* as2 = (const float*)d_in[7];
    const float* ad2 = (const float*)d_in[8];
    const float* b2  = (const float*)d_in[9];
    const float* Wc  = (const float*)d_in[10];
    const float* bc  = (const float*)d_in[11];

    const int N = in_sizes[0] / 128;
    const int E = in_sizes[1] / 2;
    const int* esrc = ei;
    const int* edst = ei + E;

    float* ws  = (float*)d_ws;
    float* H   = ws;                       // N*32
    float* AGG = H + (size_t)N * 32;       // N*32
    float* Ss  = AGG + (size_t)N * 32;     // N
    float* Sd  = Ss + N;                   // N
    float* M   = Sd + N;                   // N
    float* Z   = M + N;                    // N

    const dim3 blk(256);
    const int nb_rows = (N + 7) / 8;
    const int tot = E + N;
    const int nb_e1 = (tot + 255) / 256;
    const int nb_e8 = (tot + 7) / 8;
    const int nb_init = (N * 32 + 255) / 256;

    // ---- Layer 1 ----
    k_feat1<<<nb_rows, blk, 0, stream>>>(x, W1, as1, ad1, H, Ss, Sd, N);
    k_init<<<nb_init, blk, 0, stream>>>(M, Z, AGG, N);
    k_edge_max<<<nb_e1, blk, 0, stream>>>(esrc, edst, E, N, Ss, Sd, M);
    k_edge_sum<<<nb_e1, blk, 0, stream>>>(esrc, edst, E, N, Ss, Sd, M, Z);
    k_edge_agg<<<nb_e8, blk, 0, stream>>>(esrc, edst, E, N, Ss, Sd, M, Z, H, AGG);

    // ---- Layer 2 ----  (k_feat2 consumes AGG before k_init re-zeroes it)
    k_feat2<<<nb_rows, blk, 0, stream>>>(AGG, W2, b1, as2, ad2, H, Ss, Sd, N);
    k_init<<<nb_init, blk, 0, stream>>>(M, Z, AGG, N);
    k_edge_max<<<nb_e1, blk, 0, stream>>>(esrc, edst, E, N, Ss, Sd, M);
    k_edge_sum<<<nb_e1, blk, 0, stream>>>(esrc, edst, E, N, Ss, Sd, M, Z);
    k_edge_agg<<<nb_e8, blk, 0, stream>>>(esrc, edst, E, N, Ss, Sd, M, Z, H, AGG);

    // ---- Classifier ----
    k_cls<<<nb_rows, blk, 0, stream>>>(AGG, Wc, b2, bc, (float*)d_out, N);
}

// Round 2
// 692.001 us; speedup vs baseline: 2.0177x; 2.0177x over previous
//
#include <hip/hip_runtime.h>
#include <math.h>

#define NS 0.2f  // leaky_relu negative slope

__device__ __forceinline__ float lrelu(float x) { return x > 0.f ? x : NS * x; }

// ---------------- dense feature kernels ----------------

// H = X @ W  (N x 128 -> N x 32), plus per-node scores s_src = H@a_s, s_dst = H@a_d
__global__ __launch_bounds__(256) void k_feat1(
    const float* __restrict__ X, const float* __restrict__ W,
    const float* __restrict__ a_s, const float* __restrict__ a_d,
    float* __restrict__ H, float* __restrict__ Ss, float* __restrict__ Sd, int n)
{
    __shared__ float Wl[128 * 32];
    __shared__ float Xl[8 * 128];
    const int tid = threadIdx.x;
    for (int i = tid; i < 128 * 32; i += 256) Wl[i] = W[i];

    const int row0 = blockIdx.x * 8;
    {
        int idx = tid * 4;
        int r = idx >> 7, c = idx & 127;
        if (row0 + r < n)
            *reinterpret_cast<float4*>(&Xl[idx]) =
                *reinterpret_cast<const float4*>(&X[(size_t)(row0 + r) * 128 + c]);
    }
    __syncthreads();

    const int r = tid >> 5, c = tid & 31;
    const int row = row0 + r;
    if (row >= n) return;

    float acc = 0.f;
#pragma unroll
    for (int k = 0; k < 128; ++k) acc += Xl[r * 128 + k] * Wl[k * 32 + c];
    H[(size_t)row * 32 + c] = acc;

    float vs = acc * a_s[c];
    float vd = acc * a_d[c];
#pragma unroll
    for (int o = 16; o; o >>= 1) { vs += __shfl_xor(vs, o, 32); vd += __shfl_xor(vd, o, 32); }
    if (c == 0) { Ss[row] = vs; Sd[row] = vd; }
}

// G = relu(In + bias); H = G @ W (32x32); plus scores
__global__ __launch_bounds__(256) void k_feat2(
    const float* __restrict__ In, const float* __restrict__ W,
    const float* __restrict__ bias,
    const float* __restrict__ a_s, const float* __restrict__ a_d,
    float* __restrict__ H, float* __restrict__ Ss, float* __restrict__ Sd, int n)
{
    __shared__ float Wl[32 * 32];
    __shared__ float Xl[8 * 32];
    const int tid = threadIdx.x;
    for (int i = tid; i < 1024; i += 256) Wl[i] = W[i];

    const int r = tid >> 5, c = tid & 31;
    const int row = blockIdx.x * 8 + r;
    if (row < n) Xl[tid] = fmaxf(In[(size_t)row * 32 + c] + bias[c], 0.f);
    __syncthreads();
    if (row >= n) return;

    float acc = 0.f;
#pragma unroll
    for (int k = 0; k < 32; ++k) acc += Xl[r * 32 + k] * Wl[k * 32 + c];
    H[(size_t)row * 32 + c] = acc;

    float vs = acc * a_s[c];
    float vd = acc * a_d[c];
#pragma unroll
    for (int o = 16; o; o >>= 1) { vs += __shfl_xor(vs, o, 32); vd += __shfl_xor(vd, o, 32); }
    if (c == 0) { Ss[row] = vs; Sd[row] = vd; }
}

// Out = sigmoid( relu(In + b_prev) @ Wc + bc )
__global__ __launch_bounds__(256) void k_cls(
    const float* __restrict__ In, const float* __restrict__ W,
    const float* __restrict__ b_prev, const float* __restrict__ bc,
    float* __restrict__ Out, int n)
{
    __shared__ float Wl[32 * 32];
    __shared__ float Xl[8 * 32];
    const int tid = threadIdx.x;
    for (int i = tid; i < 1024; i += 256) Wl[i] = W[i];

    const int r = tid >> 5, c = tid & 31;
    const int row = blockIdx.x * 8 + r;
    if (row < n) Xl[tid] = fmaxf(In[(size_t)row * 32 + c] + b_prev[c], 0.f);
    __syncthreads();
    if (row >= n) return;

    float acc = bc[c];
#pragma unroll
    for (int k = 0; k < 32; ++k) acc += Xl[r * 32 + k] * Wl[k * 32 + c];
    Out[(size_t)row * 32 + c] = 1.f / (1.f + __expf(-acc));
}

// ---------------- CSR build (once per call) ----------------
// deg zeroed via hipMemsetAsync beforehand. Self-loops accounted as deg+1 in scan.

__global__ void k_hist(const int* __restrict__ edst, int E, int* __restrict__ deg)
{
    int e = blockIdx.x * 256 + threadIdx.x;
    if (e < E) atomicAdd(&deg[edst[e]], 1);
}

// chunk = 1024 elements per block (256 threads x 4). part[b] = sum of (deg+1) in chunk.
__global__ __launch_bounds__(256) void k_scan1(const int* __restrict__ deg, int n,
                                               int* __restrict__ part)
{
    int base = blockIdx.x * 1024 + threadIdx.x * 4;
    int s = 0;
#pragma unroll
    for (int k = 0; k < 4; ++k) { int i = base + k; if (i < n) s += deg[i] + 1; }
    __shared__ int sm[256];
    sm[threadIdx.x] = s; __syncthreads();
    for (int o = 128; o; o >>= 1) {
        if (threadIdx.x < o) sm[threadIdx.x] += sm[threadIdx.x + o];
        __syncthreads();
    }
    if (threadIdx.x == 0) part[blockIdx.x] = sm[0];
}

// single block: exclusive-scan part[0..nb) (nb <= 256), total -> off_n[0]
__global__ __launch_bounds__(256) void k_scan2(int* __restrict__ part, int nb,
                                               int* __restrict__ off_n)
{
    __shared__ int sm[256];
    int t = threadIdx.x;
    int v = (t < nb) ? part[t] : 0;
    sm[t] = v; __syncthreads();
    for (int o = 1; o < 256; o <<= 1) {
        int x = sm[t];
        if (t >= o) x += sm[t - o];
        __syncthreads();
        sm[t] = x;
        __syncthreads();
    }
    if (t < nb) part[t] = sm[t] - v;   // exclusive
    if (t == 255) off_n[0] = sm[255];  // total = E + n
}

// write off[i], place self-loop at segment start, cursor[i] = off[i]+1
__global__ __launch_bounds__(256) void k_scan3(const int* __restrict__ deg, int n,
    const int* __restrict__ part, int* __restrict__ off,
    int* __restrict__ cursor, int* __restrict__ esorted)
{
    int t = threadIdx.x;
    int base = blockIdx.x * 1024 + t * 4;
    int v[4]; int s = 0;
#pragma unroll
    for (int k = 0; k < 4; ++k) { int i = base + k; v[k] = (i < n) ? deg[i] + 1 : 0; s += v[k]; }
    __shared__ int sm[256];
    sm[t] = s; __syncthreads();
    for (int o = 1; o < 256; o <<= 1) {
        int x = sm[t];
        if (t >= o) x += sm[t - o];
        __syncthreads();
        sm[t] = x;
        __syncthreads();
    }
    int run = (sm[t] - s) + part[blockIdx.x];
#pragma unroll
    for (int k = 0; k < 4; ++k) {
        int i = base + k;
        if (i < n) {
            off[i] = run;
            esorted[run] = i;      // self-loop first in segment
            cursor[i] = run + 1;
            run += v[k];
        }
    }
}

__global__ void k_scatter(const int* __restrict__ esrc, const int* __restrict__ edst, int E,
                          int* __restrict__ cursor, int* __restrict__ esorted)
{
    int e = blockIdx.x * 256 + threadIdx.x;
    if (e < E) {
        int d = edst[e];
        int pos = atomicAdd(&cursor[d], 1);
        esorted[pos] = esrc[e];
    }
}

// ---------------- per-layer fused GAT aggregation ----------------

// global max of Ss -> out[0]  (single block, grid-stride)
__global__ __launch_bounds__(1024) void k_maxred(const float* __restrict__ Ss, int n,
                                                 float* __restrict__ out)
{
    float m = -INFINITY;
    for (int i = threadIdx.x; i < n; i += 1024) m = fmaxf(m, Ss[i]);
    __shared__ float sm[1024];
    sm[threadIdx.x] = m; __syncthreads();
    for (int o = 512; o; o >>= 1) {
        if (threadIdx.x < o) sm[threadIdx.x] = fmaxf(sm[threadIdx.x], sm[threadIdx.x + o]);
        __syncthreads();
    }
    if (threadIdx.x == 0) out[0] = sm[0];
}

// one 32-lane group per dst node: softmax (shifted by upper bound, exact ratio)
// + weighted aggregation of H[src], all in registers. No atomics.
__global__ __launch_bounds__(256) void k_gat(
    const int* __restrict__ off, const int* __restrict__ esorted,
    const float* __restrict__ Ss, const float* __restrict__ Sd,
    const float* __restrict__ maxSs, const float* __restrict__ H,
    float* __restrict__ out, int n)
{
    int g = blockIdx.x * 8 + (threadIdx.x >> 5);
    int lane = threadIdx.x & 31;
    if (g >= n) return;

    float sd = Sd[g];
    float ub = lrelu(maxSs[0] + sd);   // >= true segment max (lrelu monotone)
    int j = off[g], j1 = off[g + 1];

    float z = 0.f, acc = 0.f;
    for (; j + 3 < j1; j += 4) {
        int s0 = esorted[j], s1 = esorted[j + 1], s2 = esorted[j + 2], s3 = esorted[j + 3];
        float w0 = __expf(lrelu(Ss[s0] + sd) - ub);
        float w1 = __expf(lrelu(Ss[s1] + sd) - ub);
        float w2 = __expf(lrelu(Ss[s2] + sd) - ub);
        float w3 = __expf(lrelu(Ss[s3] + sd) - ub);
        float h0 = H[(size_t)s0 * 32 + lane];
        float h1 = H[(size_t)s1 * 32 + lane];
        float h2 = H[(size_t)s2 * 32 + lane];
        float h3 = H[(size_t)s3 * 32 + lane];
        z += (w0 + w1) + (w2 + w3);
        acc += w0 * h0 + w1 * h1 + w2 * h2 + w3 * h3;
    }
    for (; j < j1; ++j) {
        int s = esorted[j];
        float w = __expf(lrelu(Ss[s] + sd) - ub);
        z += w;
        acc += w * H[(size_t)s * 32 + lane];
    }
    out[(size_t)g * 32 + lane] = acc / (z + 1e-16f);
}

// ---------------- launch ----------------

extern "C" void kernel_launch(void* const* d_in, const int* in_sizes, int n_in,
                              void* d_out, int out_size, void* d_ws, size_t ws_size,
                              hipStream_t stream)
{
    const float* x   = (const float*)d_in[0];
    const int*   ei  = (const int*)d_in[1];
    const float* W1  = (const float*)d_in[2];
    const float* as1 = (const float*)d_in[3];
    const float* ad1 = (const float*)d_in[4];
    const float* b1  = (const float*)d_in[5];
    const float* W2  = (const float*)d_in[6];
    const float* as2 = (const float*)d_in[7];
    const float* ad2 = (const float*)d_in[8];
    const float* b2  = (const float*)d_in[9];
    const float* Wc  = (const float*)d_in[10];
    const float* bc  = (const float*)d_in[11];

    const int N = in_sizes[0] / 128;
    const int E = in_sizes[1] / 2;
    const int* esrc = ei;
    const int* edst = ei + E;

    // workspace carve-up (floats/ints are both 4B)
    char* p = (char*)d_ws;
    float* H     = (float*)p; p += (size_t)N * 32 * 4;   // 12.8 MB
    float* AGG   = (float*)p; p += (size_t)N * 32 * 4;   // 12.8 MB
    float* Ss    = (float*)p; p += (size_t)N * 4;
    float* Sd    = (float*)p; p += (size_t)N * 4;
    float* MSS   = (float*)p; p += 256;                  // maxSs scalar (padded)
    int*   deg   = (int*)p;   p += (size_t)N * 4;
    int*   off   = (int*)p;   p += (size_t)(N + 1) * 4;
    int*   cur   = (int*)p;   p += (size_t)N * 4;
    int*   part  = (int*)p;   p += 256 * 4;
    int*   esort = (int*)p;   p += (size_t)(E + N) * 4;  // 13.2 MB

    const dim3 blk(256);
    const int nb_rows  = (N + 7) / 8;
    const int nb_edges = (E + 255) / 256;
    const int nb_nodes = (N + 7) / 8;        // k_gat: 8 dst per block
    const int nb_chunk = (N + 1023) / 1024;  // scan chunks (requires N <= 262144)

    // ---- CSR build (by dst), shared by both layers ----
    hipMemsetAsync(deg, 0, (size_t)N * 4, stream);
    k_hist<<<nb_edges, blk, 0, stream>>>(edst, E, deg);
    k_scan1<<<nb_chunk, blk, 0, stream>>>(deg, N, part);
    k_scan2<<<1, blk, 0, stream>>>(part, nb_chunk, off + N);
    k_scan3<<<nb_chunk, blk, 0, stream>>>(deg, N, part, off, cur, esort);
    k_scatter<<<nb_edges, blk, 0, stream>>>(esrc, edst, E, cur, esort);

    // ---- Layer 1 ----
    k_feat1<<<nb_rows, blk, 0, stream>>>(x, W1, as1, ad1, H, Ss, Sd, N);
    k_maxred<<<1, 1024, 0, stream>>>(Ss, N, MSS);
    k_gat<<<nb_nodes, blk, 0, stream>>>(off, esort, Ss, Sd, MSS, H, AGG, N);

    // ---- Layer 2 ----
    k_feat2<<<nb_rows, blk, 0, stream>>>(AGG, W2, b1, as2, ad2, H, Ss, Sd, N);
    k_maxred<<<1, 1024, 0, stream>>>(Ss, N, MSS);
    k_gat<<<nb_nodes, blk, 0, stream>>>(off, esort, Ss, Sd, MSS, H, AGG, N);

    // ---- Classifier ----
    k_cls<<<nb_rows, blk, 0, stream>>>(AGG, Wc, b2, bc, (float*)d_out, N);
}

// Round 3
// 456.270 us; speedup vs baseline: 3.0601x; 1.5166x over previous
//
#include <hip/hip_runtime.h>
#include <math.h>

#define NS 0.2f  // leaky_relu negative slope

__device__ __forceinline__ float lrelu(float x) { return x > 0.f ? x : NS * x; }

// ---------------- dense feature kernels ----------------

__global__ __launch_bounds__(256) void k_feat1(
    const float* __restrict__ X, const float* __restrict__ W,
    const float* __restrict__ a_s, const float* __restrict__ a_d,
    float* __restrict__ H, float* __restrict__ Ss, float* __restrict__ Sd, int n)
{
    __shared__ float Wl[128 * 32];
    __shared__ float Xl[8 * 128];
    const int tid = threadIdx.x;
    for (int i = tid; i < 128 * 32; i += 256) Wl[i] = W[i];

    const int row0 = blockIdx.x * 8;
    {
        int idx = tid * 4;
        int r = idx >> 7, c = idx & 127;
        if (row0 + r < n)
            *reinterpret_cast<float4*>(&Xl[idx]) =
                *reinterpret_cast<const float4*>(&X[(size_t)(row0 + r) * 128 + c]);
    }
    __syncthreads();

    const int r = tid >> 5, c = tid & 31;
    const int row = row0 + r;
    if (row >= n) return;

    float acc = 0.f;
#pragma unroll
    for (int k = 0; k < 128; ++k) acc += Xl[r * 128 + k] * Wl[k * 32 + c];
    H[(size_t)row * 32 + c] = acc;

    float vs = acc * a_s[c];
    float vd = acc * a_d[c];
#pragma unroll
    for (int o = 16; o; o >>= 1) { vs += __shfl_xor(vs, o, 32); vd += __shfl_xor(vd, o, 32); }
    if (c == 0) { Ss[row] = vs; Sd[row] = vd; }
}

__global__ __launch_bounds__(256) void k_feat2(
    const float* __restrict__ In, const float* __restrict__ W,
    const float* __restrict__ bias,
    const float* __restrict__ a_s, const float* __restrict__ a_d,
    float* __restrict__ H, float* __restrict__ Ss, float* __restrict__ Sd, int n)
{
    __shared__ float Wl[32 * 32];
    __shared__ float Xl[8 * 32];
    const int tid = threadIdx.x;
    for (int i = tid; i < 1024; i += 256) Wl[i] = W[i];

    const int r = tid >> 5, c = tid & 31;
    const int row = blockIdx.x * 8 + r;
    if (row < n) Xl[tid] = fmaxf(In[(size_t)row * 32 + c] + bias[c], 0.f);
    __syncthreads();
    if (row >= n) return;

    float acc = 0.f;
#pragma unroll
    for (int k = 0; k < 32; ++k) acc += Xl[r * 32 + k] * Wl[k * 32 + c];
    H[(size_t)row * 32 + c] = acc;

    float vs = acc * a_s[c];
    float vd = acc * a_d[c];
#pragma unroll
    for (int o = 16; o; o >>= 1) { vs += __shfl_xor(vs, o, 32); vd += __shfl_xor(vd, o, 32); }
    if (c == 0) { Ss[row] = vs; Sd[row] = vd; }
}

__global__ __launch_bounds__(256) void k_cls(
    const float* __restrict__ In, const float* __restrict__ W,
    const float* __restrict__ b_prev, const float* __restrict__ bc,
    float* __restrict__ Out, int n)
{
    __shared__ float Wl[32 * 32];
    __shared__ float Xl[8 * 32];
    const int tid = threadIdx.x;
    for (int i = tid; i < 1024; i += 256) Wl[i] = W[i];

    const int r = tid >> 5, c = tid & 31;
    const int row = blockIdx.x * 8 + r;
    if (row < n) Xl[tid] = fmaxf(In[(size_t)row * 32 + c] + b_prev[c], 0.f);
    __syncthreads();
    if (row >= n) return;

    float acc = bc[c];
#pragma unroll
    for (int k = 0; k < 32; ++k) acc += Xl[r * 32 + k] * Wl[k * 32 + c];
    Out[(size_t)row * 32 + c] = 1.f / (1.f + __expf(-acc));
}

// ---------------- CSR build ----------------

__global__ void k_hist(const int* __restrict__ edst, int E, int* __restrict__ deg)
{
    int i4 = (blockIdx.x * 256 + threadIdx.x) * 4;
    if (i4 >= E) return;
    if (i4 + 3 < E) {
        int4 d = *reinterpret_cast<const int4*>(&edst[i4]);
        atomicAdd(&deg[d.x], 1); atomicAdd(&deg[d.y], 1);
        atomicAdd(&deg[d.z], 1); atomicAdd(&deg[d.w], 1);
    } else {
        for (int k = i4; k < E; ++k) atomicAdd(&deg[edst[k]], 1);
    }
}

__global__ __launch_bounds__(256) void k_scan1(const int* __restrict__ deg, int n,
                                               int* __restrict__ part)
{
    int base = blockIdx.x * 1024 + threadIdx.x * 4;
    int s = 0;
#pragma unroll
    for (int k = 0; k < 4; ++k) { int i = base + k; if (i < n) s += deg[i] + 1; }
    __shared__ int sm[256];
    sm[threadIdx.x] = s; __syncthreads();
    for (int o = 128; o; o >>= 1) {
        if (threadIdx.x < o) sm[threadIdx.x] += sm[threadIdx.x + o];
        __syncthreads();
    }
    if (threadIdx.x == 0) part[blockIdx.x] = sm[0];
}

__global__ __launch_bounds__(256) void k_scan2(int* __restrict__ part, int nb,
                                               int* __restrict__ off_n)
{
    __shared__ int sm[256];
    int t = threadIdx.x;
    int v = (t < nb) ? part[t] : 0;
    sm[t] = v; __syncthreads();
    for (int o = 1; o < 256; o <<= 1) {
        int x = sm[t];
        if (t >= o) x += sm[t - o];
        __syncthreads();
        sm[t] = x;
        __syncthreads();
    }
    if (t < nb) part[t] = sm[t] - v;
    if (t == 255) off_n[0] = sm[255];
}

__global__ __launch_bounds__(256) void k_scan3(const int* __restrict__ deg, int n,
    const int* __restrict__ part, int* __restrict__ off)
{
    int t = threadIdx.x;
    int base = blockIdx.x * 1024 + t * 4;
    int v[4]; int s = 0;
#pragma unroll
    for (int k = 0; k < 4; ++k) { int i = base + k; v[k] = (i < n) ? deg[i] + 1 : 0; s += v[k]; }
    __shared__ int sm[256];
    sm[t] = s; __syncthreads();
    for (int o = 1; o < 256; o <<= 1) {
        int x = sm[t];
        if (t >= o) x += sm[t - o];
        __syncthreads();
        sm[t] = x;
        __syncthreads();
    }
    int run = (sm[t] - s) + part[blockIdx.x];
#pragma unroll
    for (int k = 0; k < 4; ++k) {
        int i = base + k;
        if (i < n) { off[i] = run; run += v[k]; }
    }
}

// bcur[b] = start of bucket b's edge region in ebuf (= off[256b] - 256b, self-loops excluded)
__global__ void k_binit(const int* __restrict__ off, int* __restrict__ bcur,
                        int N, int ngroups)
{
    int b = blockIdx.x * 256 + threadIdx.x;
    if (b <= ngroups) { int d = min(b << 8, N); bcur[b] = off[d] - d; }
}

// pass 1: partition (src,dst) by dst>>8 into ebuf, per-block LDS staging -> run writes
#define CHUNK 4096
#define KPT 16

__global__ __launch_bounds__(256) void k_part(
    const int* __restrict__ esrc, const int* __restrict__ edst, int E,
    int* __restrict__ bcur, unsigned long long* __restrict__ ebuf, int ngroups)
{
    __shared__ int hist[512];
    __shared__ int lofs[513];
    __shared__ int gbase[512];
    __shared__ unsigned long long stage[CHUNK];
    const int tid = threadIdx.x;

    for (int c0 = blockIdx.x * CHUNK; c0 < E; c0 += gridDim.x * CHUNK) {
        const int cnt = min(CHUNK, E - c0);
        for (int i = tid; i < 512; i += 256) hist[i] = 0;
        __syncthreads();

        int bp[KPT];
#pragma unroll
        for (int k = 0; k < KPT; ++k) {
            int i = c0 + k * 256 + tid;
            bp[k] = -1;
            if (i < E) {
                int b = edst[i] >> 8;
                int pos = atomicAdd(&hist[b], 1);
                bp[k] = (b << 13) | pos;
            }
        }
        __syncthreads();

        if (tid < 64) {           // exclusive scan of hist[0..512) by one wave
            int base = tid * 8, v[8], s = 0;
#pragma unroll
            for (int k = 0; k < 8; ++k) { v[k] = hist[base + k]; s += v[k]; }
            int pre = s;
            for (int o = 1; o < 64; o <<= 1) {
                int t2 = __shfl_up(pre, o, 64);
                if (tid >= o) pre += t2;
            }
            pre -= s;
#pragma unroll
            for (int k = 0; k < 8; ++k) { lofs[base + k] = pre; pre += v[k]; }
            if (tid == 63) lofs[512] = pre;
        }
        __syncthreads();

        for (int b = tid; b < ngroups; b += 256)
            if (hist[b] > 0) gbase[b] = atomicAdd(&bcur[b], hist[b]);
        __syncthreads();

#pragma unroll
        for (int k = 0; k < KPT; ++k) {
            if (bp[k] >= 0) {
                int i = c0 + k * 256 + tid;
                int b = bp[k] >> 13, pos = bp[k] & 8191;
                stage[lofs[b] + pos] =
                    ((unsigned long long)(unsigned)edst[i] << 32) | (unsigned)esrc[i];
            }
        }
        __syncthreads();

        for (int i = tid; i < cnt; i += 256) {
            int b = 0;   // largest b with lofs[b] <= i
            for (int step = 256; step; step >>= 1)
                if (b + step <= 512 && lofs[b + step] <= i) b += step;
            ebuf[(size_t)gbase[b] + (i - lofs[b])] = stage[i];
        }
        __syncthreads();
    }
}

// pass 2: one block per bucket; build esorted region in LDS, write coalesced.
#define RCAP 11264  // 44KB

__global__ __launch_bounds__(256) void k_place(
    const unsigned long long* __restrict__ ebuf, const int* __restrict__ off,
    int* __restrict__ esorted, int* __restrict__ gcur, int N)
{
    __shared__ int R[RCAP];
    __shared__ int lcur[256];
    const int g = blockIdx.x, tid = threadIdx.x;
    const int d0 = g << 8, d1 = min(d0 + 256, N);
    const int nd = d1 - d0;
    const int base = off[d0];
    const int len = off[d1] - base;          // edges + self-loops in region
    const int es = base - d0;                // edge start in ebuf
    const int ecnt = (off[d1] - d1) - es;

    if (len <= RCAP) {
        if (tid < nd) {
            int d = d0 + tid, o = off[d] - base;
            R[o] = d;                        // self-loop at segment head
            lcur[tid] = o + 1;
        }
        __syncthreads();
        for (int i = tid; i < ecnt; i += 256) {
            unsigned long long p = ebuf[es + i];
            int dst = (int)(p >> 32), src = (int)(p & 0xffffffffu);
            int pos = atomicAdd(&lcur[dst - d0], 1);
            R[pos] = src;
        }
        __syncthreads();
        for (int i = tid; i < len; i += 256) esorted[base + i] = R[i];
    } else {                                  // overflow fallback (never expected)
        if (tid < nd) { int d = d0 + tid; esorted[off[d]] = d; gcur[d] = off[d] + 1; }
        __syncthreads();
        for (int i = tid; i < ecnt; i += 256) {
            unsigned long long p = ebuf[es + i];
            int dst = (int)(p >> 32), src = (int)(p & 0xffffffffu);
            esorted[atomicAdd(&gcur[dst], 1)] = src;
        }
    }
}

// ---------------- global max of Ss (two stage) ----------------

__global__ __launch_bounds__(256) void k_max1(const float* __restrict__ Ss, int n,
                                              float* __restrict__ part)
{
    float m = -INFINITY;
    for (int i = blockIdx.x * 256 + threadIdx.x; i < n; i += gridDim.x * 256)
        m = fmaxf(m, Ss[i]);
    __shared__ float sm[256];
    sm[threadIdx.x] = m; __syncthreads();
    for (int o = 128; o; o >>= 1) {
        if (threadIdx.x < o) sm[threadIdx.x] = fmaxf(sm[threadIdx.x], sm[threadIdx.x + o]);
        __syncthreads();
    }
    if (threadIdx.x == 0) part[blockIdx.x] = sm[0];
}

__global__ void k_max2(const float* __restrict__ part, int nb, float* __restrict__ out)
{
    float m = -INFINITY;
    for (int i = threadIdx.x; i < nb; i += 64) m = fmaxf(m, part[i]);
    for (int o = 32; o; o >>= 1) m = fmaxf(m, __shfl_xor(m, o, 64));
    if (threadIdx.x == 0) out[0] = m;
}

// ---------------- fused GAT aggregation ----------------

__global__ __launch_bounds__(256) void k_gat(
    const int* __restrict__ off, const int* __restrict__ esorted,
    const float* __restrict__ Ss, const float* __restrict__ Sd,
    const float* __restrict__ maxSs, const float* __restrict__ H,
    float* __restrict__ out, int n)
{
    int g = blockIdx.x * 8 + (threadIdx.x >> 5);
    int lane = threadIdx.x & 31;
    if (g >= n) return;

    float sd = Sd[g];
    float ub = lrelu(maxSs[0] + sd);   // >= true segment max (lrelu monotone)
    int j = off[g], j1 = off[g + 1];

    float z = 0.f, acc = 0.f;
    for (; j + 3 < j1; j += 4) {
        int s0 = esorted[j], s1 = esorted[j + 1], s2 = esorted[j + 2], s3 = esorted[j + 3];
        float w0 = __expf(lrelu(Ss[s0] + sd) - ub);
        float w1 = __expf(lrelu(Ss[s1] + sd) - ub);
        float w2 = __expf(lrelu(Ss[s2] + sd) - ub);
        float w3 = __expf(lrelu(Ss[s3] + sd) - ub);
        float h0 = H[(size_t)s0 * 32 + lane];
        float h1 = H[(size_t)s1 * 32 + lane];
        float h2 = H[(size_t)s2 * 32 + lane];
        float h3 = H[(size_t)s3 * 32 + lane];
        z += (w0 + w1) + (w2 + w3);
        acc += w0 * h0 + w1 * h1 + w2 * h2 + w3 * h3;
    }
    for (; j < j1; ++j) {
        int s = esorted[j];
        float w = __expf(lrelu(Ss[s] + sd) - ub);
        z += w;
        acc += w * H[(size_t)s * 32 + lane];
    }
    out[(size_t)g * 32 + lane] = acc / (z + 1e-16f);
}

// ---------------- launch ----------------

extern "C" void kernel_launch(void* const* d_in, const int* in_sizes, int n_in,
                              void* d_out, int out_size, void* d_ws, size_t ws_size,
                              hipStream_t stream)
{
    const float* x   = (const float*)d_in[0];
    const int*   ei  = (const int*)d_in[1];
    const float* W1  = (const float*)d_in[2];
    const float* as1 = (const float*)d_in[3];
    const float* ad1 = (const float*)d_in[4];
    const float* b1  = (const float*)d_in[5];
    const float* W2  = (const float*)d_in[6];
    const float* as2 = (const float*)d_in[7];
    const float* ad2 = (const float*)d_in[8];
    const float* b2  = (const float*)d_in[9];
    const float* Wc  = (const float*)d_in[10];
    const float* bc  = (const float*)d_in[11];

    const int N = in_sizes[0] / 128;
    const int E = in_sizes[1] / 2;
    const int* esrc = ei;
    const int* edst = ei + E;
    const int ngroups = (N + 255) >> 8;

    // workspace carve-up
    char* p = (char*)d_ws;
    float* H     = (float*)p; p += (size_t)N * 32 * 4;   // 12.8 MB ┐ ebuf aliases
    float* AGG   = (float*)p; p += (size_t)N * 32 * 4;   // 12.8 MB ┘ H+AGG (build phase only)
    float* Ss    = (float*)p; p += (size_t)N * 4;
    float* Sd    = (float*)p; p += (size_t)N * 4;
    float* MSS   = (float*)p; p += 256;
    int*   deg   = (int*)p;   p += (size_t)N * 4;        // also gcur fallback
    int*   off   = (int*)p;   p += (size_t)(N + 1) * 4;
    int*   part  = (int*)p;   p += 256 * 4;              // scan partials / max partials
    int*   bcur  = (int*)p;   p += 512 * 4;
    int*   esort = (int*)p;   p += (size_t)(E + N) * 4;  // 13.2 MB

    unsigned long long* ebuf = (unsigned long long*)H;   // 25.6 MB alias over H+AGG

    const dim3 blk(256);
    const int nb_rows  = (N + 7) / 8;
    const int nb_hist  = (E / 4 + 255) / 256;
    const int nb_chunk = (N + 1023) / 1024;

    // ---- CSR build (by dst), shared by both layers ----
    hipMemsetAsync(deg, 0, (size_t)N * 4, stream);
    k_hist<<<nb_hist, blk, 0, stream>>>(edst, E, deg);
    k_scan1<<<nb_chunk, blk, 0, stream>>>(deg, N, part);
    k_scan2<<<1, blk, 0, stream>>>(part, nb_chunk, off + N);
    k_scan3<<<nb_chunk, blk, 0, stream>>>(deg, N, part, off);
    k_binit<<<(ngroups + 256) / 256, blk, 0, stream>>>(off, bcur, N, ngroups);
    k_part<<<768, blk, 0, stream>>>(esrc, edst, E, bcur, ebuf, ngroups);
    k_place<<<ngroups, blk, 0, stream>>>(ebuf, off, esort, deg /*gcur fallback*/, N);

    // ---- Layer 1 ----  (feat1 overwrites H => ebuf dead from here on)
    k_feat1<<<nb_rows, blk, 0, stream>>>(x, W1, as1, ad1, H, Ss, Sd, N);
    k_max1<<<128, blk, 0, stream>>>(Ss, N, (float*)part);
    k_max2<<<1, 64, 0, stream>>>((float*)part, 128, MSS);
    k_gat<<<(N + 7) / 8, blk, 0, stream>>>(off, esort, Ss, Sd, MSS, H, AGG, N);

    // ---- Layer 2 ----
    k_feat2<<<nb_rows, blk, 0, stream>>>(AGG, W2, b1, as2, ad2, H, Ss, Sd, N);
    k_max1<<<128, blk, 0, stream>>>(Ss, N, (float*)part);
    k_max2<<<1, 64, 0, stream>>>((float*)part, 128, MSS);
    k_gat<<<(N + 7) / 8, blk, 0, stream>>>(off, esort, Ss, Sd, MSS, H, AGG, N);

    // ---- Classifier ----
    k_cls<<<nb_rows, blk, 0, stream>>>(AGG, Wc, b2, bc, (float*)d_out, N);
}

// Round 4
// 404.554 us; speedup vs baseline: 3.4513x; 1.1278x over previous
//
#include <hip/hip_runtime.h>
#include <math.h>

#define NS 0.2f  // leaky_relu negative slope

__device__ __forceinline__ float lrelu(float x) { return x > 0.f ? x : NS * x; }

// ---------------- dense feature kernels ----------------

__global__ __launch_bounds__(256) void k_feat1(
    const float* __restrict__ X, const float* __restrict__ W,
    const float* __restrict__ a_s, const float* __restrict__ a_d,
    float* __restrict__ H, float* __restrict__ Ss, float* __restrict__ Sd, int n)
{
    __shared__ float Wl[128 * 32];
    __shared__ float Xl[8 * 128];
    const int tid = threadIdx.x;
    for (int i = tid; i < 128 * 32; i += 256) Wl[i] = W[i];

    const int row0 = blockIdx.x * 8;
    {
        int idx = tid * 4;
        int r = idx >> 7, c = idx & 127;
        if (row0 + r < n)
            *reinterpret_cast<float4*>(&Xl[idx]) =
                *reinterpret_cast<const float4*>(&X[(size_t)(row0 + r) * 128 + c]);
    }
    __syncthreads();

    const int r = tid >> 5, c = tid & 31;
    const int row = row0 + r;
    if (row >= n) return;

    float acc = 0.f;
#pragma unroll
    for (int k = 0; k < 128; ++k) acc += Xl[r * 128 + k] * Wl[k * 32 + c];
    H[(size_t)row * 32 + c] = acc;

    float vs = acc * a_s[c];
    float vd = acc * a_d[c];
#pragma unroll
    for (int o = 16; o; o >>= 1) { vs += __shfl_xor(vs, o, 32); vd += __shfl_xor(vd, o, 32); }
    if (c == 0) { Ss[row] = vs; Sd[row] = vd; }
}

__global__ __launch_bounds__(256) void k_feat2(
    const float* __restrict__ In, const float* __restrict__ W,
    const float* __restrict__ bias,
    const float* __restrict__ a_s, const float* __restrict__ a_d,
    float* __restrict__ H, float* __restrict__ Ss, float* __restrict__ Sd, int n)
{
    __shared__ float Wl[32 * 32];
    __shared__ float Xl[8 * 32];
    const int tid = threadIdx.x;
    for (int i = tid; i < 1024; i += 256) Wl[i] = W[i];

    const int r = tid >> 5, c = tid & 31;
    const int row = blockIdx.x * 8 + r;
    if (row < n) Xl[tid] = fmaxf(In[(size_t)row * 32 + c] + bias[c], 0.f);
    __syncthreads();
    if (row >= n) return;

    float acc = 0.f;
#pragma unroll
    for (int k = 0; k < 32; ++k) acc += Xl[r * 32 + k] * Wl[k * 32 + c];
    H[(size_t)row * 32 + c] = acc;

    float vs = acc * a_s[c];
    float vd = acc * a_d[c];
#pragma unroll
    for (int o = 16; o; o >>= 1) { vs += __shfl_xor(vs, o, 32); vd += __shfl_xor(vd, o, 32); }
    if (c == 0) { Ss[row] = vs; Sd[row] = vd; }
}

__global__ __launch_bounds__(256) void k_cls(
    const float* __restrict__ In, const float* __restrict__ W,
    const float* __restrict__ b_prev, const float* __restrict__ bc,
    float* __restrict__ Out, int n)
{
    __shared__ float Wl[32 * 32];
    __shared__ float Xl[8 * 32];
    const int tid = threadIdx.x;
    for (int i = tid; i < 1024; i += 256) Wl[i] = W[i];

    const int r = tid >> 5, c = tid & 31;
    const int row = blockIdx.x * 8 + r;
    if (row < n) Xl[tid] = fmaxf(In[(size_t)row * 32 + c] + b_prev[c], 0.f);
    __syncthreads();
    if (row >= n) return;

    float acc = bc[c];
#pragma unroll
    for (int k = 0; k < 32; ++k) acc += Xl[r * 32 + k] * Wl[k * 32 + c];
    Out[(size_t)row * 32 + c] = 1.f / (1.f + __expf(-acc));
}

// ---------------- bucketed CSR build ----------------
// Buckets of 256 consecutive dst nodes. ngroups = ceil(N/256) (must be <= 511).

// coarse bucket histogram, LDS-privatized
__global__ __launch_bounds__(256) void k_bhist(const int* __restrict__ edst, int E,
                                               int* __restrict__ bcnt, int ngroups)
{
    __shared__ int h[512];
    const int tid = threadIdx.x;
    for (int i = tid; i < ngroups; i += 256) h[i] = 0;
    __syncthreads();
    int i4 = (blockIdx.x * 256 + tid) * 4;
    if (i4 + 3 < E) {
        int4 d = *reinterpret_cast<const int4*>(&edst[i4]);
        atomicAdd(&h[d.x >> 8], 1); atomicAdd(&h[d.y >> 8], 1);
        atomicAdd(&h[d.z >> 8], 1); atomicAdd(&h[d.w >> 8], 1);
    } else {
        for (int k = i4; k < E; ++k) atomicAdd(&h[edst[k] >> 8], 1);
    }
    __syncthreads();
    for (int i = tid; i < ngroups; i += 256)
        if (h[i] > 0) atomicAdd(&bcnt[i], h[i]);
}

// single block: exclusive scan of bcnt -> bstart[0..ngroups]; init bcur; off[N]=E+N
__global__ __launch_bounds__(512) void k_bscan(const int* __restrict__ bcnt, int ngroups,
    int* __restrict__ bstart, int* __restrict__ bcur, int* __restrict__ off,
    int N, int E)
{
    __shared__ int sm[512];
    int t = threadIdx.x;
    int v = (t < ngroups) ? bcnt[t] : 0;
    sm[t] = v; __syncthreads();
    for (int o = 1; o < 512; o <<= 1) {
        int x = sm[t];
        if (t >= o) x += sm[t - o];
        __syncthreads();
        sm[t] = x;
        __syncthreads();
    }
    if (t <= ngroups) {
        int ex = (t == 0) ? 0 : sm[t - 1];
        bstart[t] = ex;
        if (t < ngroups) bcur[t] = ex;
    }
    if (t == 0) off[N] = E + N;
}

// pass 1: partition packed records (dstlow<<24 | src) by dst>>8 into ebuf
#define CHUNK 4096
#define KPT 16

__global__ __launch_bounds__(256) void k_part(
    const int* __restrict__ esrc, const int* __restrict__ edst, int E,
    int* __restrict__ bcur, unsigned int* __restrict__ ebuf, int ngroups)
{
    __shared__ int hist[512];
    __shared__ int lofs[513];
    __shared__ int gbase[512];
    __shared__ unsigned int stage[CHUNK];
    const int tid = threadIdx.x;

    for (int c0 = blockIdx.x * CHUNK; c0 < E; c0 += gridDim.x * CHUNK) {
        const int cnt = min(CHUNK, E - c0);
        for (int i = tid; i < 512; i += 256) hist[i] = 0;
        __syncthreads();

        int bp[KPT];   // (b<<20) | (dstlow<<12) | pos   (pos < 4096)
#pragma unroll
        for (int k = 0; k < KPT; ++k) {
            int i = c0 + k * 256 + tid;
            bp[k] = -1;
            if (i < E) {
                int d = edst[i];
                int b = d >> 8;
                int pos = atomicAdd(&hist[b], 1);
                bp[k] = (b << 20) | ((d & 255) << 12) | pos;
            }
        }
        __syncthreads();

        if (tid < 64) {           // exclusive scan of hist[0..512) by one wave
            int base = tid * 8, v[8], s = 0;
#pragma unroll
            for (int k = 0; k < 8; ++k) { v[k] = hist[base + k]; s += v[k]; }
            int pre = s;
            for (int o = 1; o < 64; o <<= 1) {
                int t2 = __shfl_up(pre, o, 64);
                if (tid >= o) pre += t2;
            }
            pre -= s;
#pragma unroll
            for (int k = 0; k < 8; ++k) { lofs[base + k] = pre; pre += v[k]; }
            if (tid == 63) lofs[512] = pre;
        }
        __syncthreads();

        for (int b = tid; b < ngroups; b += 256)
            if (hist[b] > 0) gbase[b] = atomicAdd(&bcur[b], hist[b]);
        __syncthreads();

#pragma unroll
        for (int k = 0; k < KPT; ++k) {
            if (bp[k] >= 0) {
                int i = c0 + k * 256 + tid;
                int b = bp[k] >> 20, dl = (bp[k] >> 12) & 255, pos = bp[k] & 4095;
                stage[lofs[b] + pos] = ((unsigned)dl << 24) | (unsigned)esrc[i];
            }
        }
        __syncthreads();

        for (int i = tid; i < cnt; i += 256) {
            int b = 0;   // largest b with lofs[b] <= i  (lands on nonempty bucket)
            for (int step = 256; step; step >>= 1)
                if (b + step <= 512 && lofs[b + step] <= i) b += step;
            ebuf[(size_t)gbase[b] + (i - lofs[b])] = stage[i];
        }
        __syncthreads();
    }
}

// pass 2: one block per bucket. Count per-node degree in LDS, scan (+self-loop),
// write off[] and the sorted segment fully coalesced.
#define RCAP 11264  // 44KB

__global__ __launch_bounds__(256) void k_place2(
    const unsigned int* __restrict__ ebuf, const int* __restrict__ bstart,
    int* __restrict__ off, int* __restrict__ esorted, int* __restrict__ gcur, int N)
{
    __shared__ int R[RCAP];
    __shared__ int cnt[256];
    __shared__ int lcur[256];
    __shared__ int sm[256];
    const int g = blockIdx.x, tid = threadIdx.x;
    const int d0 = g << 8, d1 = min(d0 + 256, N);
    const int nd = d1 - d0;
    const int eb = bstart[g];
    const int ecnt = bstart[g + 1] - eb;
    const int base = eb + d0;               // segment start incl. preceding self-loops
    const int len = ecnt + nd;

    cnt[tid] = 0;
    __syncthreads();
    for (int i = tid; i < ecnt; i += 256)
        atomicAdd(&cnt[ebuf[eb + i] >> 24], 1);
    __syncthreads();

    // inclusive scan of (cnt[t]+1)
    int v = (tid < nd) ? cnt[tid] + 1 : 0;
    sm[tid] = v; __syncthreads();
    for (int o = 1; o < 256; o <<= 1) {
        int x = sm[tid];
        if (tid >= o) x += sm[tid - o];
        __syncthreads();
        sm[tid] = x;
        __syncthreads();
    }
    int lo = sm[tid] - v;                    // exclusive

    if (len <= RCAP) {
        if (tid < nd) {
            off[d0 + tid] = base + lo;
            R[lo] = d0 + tid;                // self-loop at segment head
            lcur[tid] = lo + 1;
        }
        __syncthreads();
        for (int i = tid; i < ecnt; i += 256) {
            unsigned int w = ebuf[eb + i];
            int pos = atomicAdd(&lcur[w >> 24], 1);
            R[pos] = (int)(w & 0xffffffu);
        }
        __syncthreads();
        for (int i = tid; i < len; i += 256) esorted[base + i] = R[i];
    } else {                                 // overflow fallback (statistically never)
        if (tid < nd) {
            off[d0 + tid] = base + lo;
            esorted[base + lo] = d0 + tid;
            gcur[d0 + tid] = base + lo + 1;
        }
        __syncthreads();
        for (int i = tid; i < ecnt; i += 256) {
            unsigned int w = ebuf[eb + i];
            esorted[atomicAdd(&gcur[d0 + (int)(w >> 24)], 1)] = (int)(w & 0xffffffu);
        }
    }
}

// ---------------- global max of Ss (two stage) ----------------

__global__ __launch_bounds__(256) void k_max1(const float* __restrict__ Ss, int n,
                                              float* __restrict__ part)
{
    float m = -INFINITY;
    for (int i = blockIdx.x * 256 + threadIdx.x; i < n; i += gridDim.x * 256)
        m = fmaxf(m, Ss[i]);
    __shared__ float sm[256];
    sm[threadIdx.x] = m; __syncthreads();
    for (int o = 128; o; o >>= 1) {
        if (threadIdx.x < o) sm[threadIdx.x] = fmaxf(sm[threadIdx.x], sm[threadIdx.x + o]);
        __syncthreads();
    }
    if (threadIdx.x == 0) part[blockIdx.x] = sm[0];
}

__global__ void k_max2(const float* __restrict__ part, int nb, float* __restrict__ out)
{
    float m = -INFINITY;
    for (int i = threadIdx.x; i < nb; i += 64) m = fmaxf(m, part[i]);
    for (int o = 32; o; o >>= 1) m = fmaxf(m, __shfl_xor(m, o, 64));
    if (threadIdx.x == 0) out[0] = m;
}

// ---------------- fused GAT aggregation ----------------

__global__ __launch_bounds__(256) void k_gat(
    const int* __restrict__ off, const int* __restrict__ esorted,
    const float* __restrict__ Ss, const float* __restrict__ Sd,
    const float* __restrict__ maxSs, const float* __restrict__ H,
    float* __restrict__ out, int n)
{
    int g = blockIdx.x * 8 + (threadIdx.x >> 5);
    int lane = threadIdx.x & 31;
    if (g >= n) return;

    float sd = Sd[g];
    float ub = lrelu(maxSs[0] + sd);   // >= true segment max (lrelu monotone)
    int j = off[g], j1 = off[g + 1];

    float z = 0.f, acc = 0.f;
    for (; j + 3 < j1; j += 4) {
        int s0 = esorted[j], s1 = esorted[j + 1], s2 = esorted[j + 2], s3 = esorted[j + 3];
        float w0 = __expf(lrelu(Ss[s0] + sd) - ub);
        float w1 = __expf(lrelu(Ss[s1] + sd) - ub);
        float w2 = __expf(lrelu(Ss[s2] + sd) - ub);
        float w3 = __expf(lrelu(Ss[s3] + sd) - ub);
        float h0 = H[(size_t)s0 * 32 + lane];
        float h1 = H[(size_t)s1 * 32 + lane];
        float h2 = H[(size_t)s2 * 32 + lane];
        float h3 = H[(size_t)s3 * 32 + lane];
        z += (w0 + w1) + (w2 + w3);
        acc += w0 * h0 + w1 * h1 + w2 * h2 + w3 * h3;
    }
    for (; j < j1; ++j) {
        int s = esorted[j];
        float w = __expf(lrelu(Ss[s] + sd) - ub);
        z += w;
        acc += w * H[(size_t)s * 32 + lane];
    }
    out[(size_t)g * 32 + lane] = acc / (z + 1e-16f);
}

// ---------------- launch ----------------

extern "C" void kernel_launch(void* const* d_in, const int* in_sizes, int n_in,
                              void* d_out, int out_size, void* d_ws, size_t ws_size,
                              hipStream_t stream)
{
    const float* x   = (const float*)d_in[0];
    const int*   ei  = (const int*)d_in[1];
    const float* W1  = (const float*)d_in[2];
    const float* as1 = (const float*)d_in[3];
    const float* ad1 = (const float*)d_in[4];
    const float* b1  = (const float*)d_in[5];
    const float* W2  = (const float*)d_in[6];
    const float* as2 = (const float*)d_in[7];
    const float* ad2 = (const float*)d_in[8];
    const float* b2  = (const float*)d_in[9];
    const float* Wc  = (const float*)d_in[10];
    const float* bc  = (const float*)d_in[11];

    const int N = in_sizes[0] / 128;
    const int E = in_sizes[1] / 2;
    const int* esrc = ei;
    const int* edst = ei + E;
    const int ngroups = (N + 255) >> 8;      // must be <= 511

    // workspace carve-up
    char* p = (char*)d_ws;
    float* H     = (float*)p; p += (size_t)N * 32 * 4;   // 12.8 MB  (ebuf aliases H)
    float* AGG   = (float*)p; p += (size_t)N * 32 * 4;   // 12.8 MB
    float* Ss    = (float*)p; p += (size_t)N * 4;
    float* Sd    = (float*)p; p += (size_t)N * 4;
    float* MSS   = (float*)p; p += 256;
    int*   off   = (int*)p;   p += (size_t)(N + 1) * 4;
    int*   gcur  = (int*)p;   p += (size_t)N * 4;        // overflow fallback only
    int*   part  = (int*)p;   p += 256 * 4;              // max partials
    int*   bcnt  = (int*)p;   p += 512 * 4;
    int*   bstart= (int*)p;   p += 513 * 4;
    int*   bcur  = (int*)p;   p += 512 * 4;
    int*   esort = (int*)p;   p += (size_t)(E + N) * 4;  // 13.2 MB

    unsigned int* ebuf = (unsigned int*)H;               // 12.8 MB alias (build only)

    const dim3 blk(256);
    const int nb_rows = (N + 7) / 8;
    const int nb_bh   = (E + 1023) / 1024;

    // ---- bucketed CSR build (by dst), shared by both layers ----
    hipMemsetAsync(bcnt, 0, 512 * 4, stream);
    k_bhist<<<nb_bh, blk, 0, stream>>>(edst, E, bcnt, ngroups);
    k_bscan<<<1, 512, 0, stream>>>(bcnt, ngroups, bstart, bcur, off, N, E);
    k_part<<<768, blk, 0, stream>>>(esrc, edst, E, bcur, ebuf, ngroups);
    k_place2<<<ngroups, blk, 0, stream>>>(ebuf, bstart, off, esort, gcur, N);

    // ---- Layer 1 ----  (feat1 overwrites H => ebuf dead from here on)
    k_feat1<<<nb_rows, blk, 0, stream>>>(x, W1, as1, ad1, H, Ss, Sd, N);
    k_max1<<<128, blk, 0, stream>>>(Ss, N, (float*)part);
    k_max2<<<1, 64, 0, stream>>>((float*)part, 128, MSS);
    k_gat<<<(N + 7) / 8, blk, 0, stream>>>(off, esort, Ss, Sd, MSS, H, AGG, N);

    // ---- Layer 2 ----
    k_feat2<<<nb_rows, blk, 0, stream>>>(AGG, W2, b1, as2, ad2, H, Ss, Sd, N);
    k_max1<<<128, blk, 0, stream>>>(Ss, N, (float*)part);
    k_max2<<<1, 64, 0, stream>>>((float*)part, 128, MSS);
    k_gat<<<(N + 7) / 8, blk, 0, stream>>>(off, esort, Ss, Sd, MSS, H, AGG, N);

    // ---- Classifier ----
    k_cls<<<nb_rows, blk, 0, stream>>>(AGG, Wc, b2, bc, (float*)d_out, N);
}

// Round 5
// 334.345 us; speedup vs baseline: 4.1760x; 1.2100x over previous
//
#include <hip/hip_runtime.h>
#include <math.h>

#define NS 0.2f  // leaky_relu negative slope

__device__ __forceinline__ float lrelu(float x) { return x > 0.f ? x : NS * x; }

// ---------------- dense feature kernels ----------------

__global__ __launch_bounds__(256) void k_feat1(
    const float* __restrict__ X, const float* __restrict__ W,
    const float* __restrict__ a_s, const float* __restrict__ a_d,
    float* __restrict__ H, float* __restrict__ Ss, float* __restrict__ Sd, int n)
{
    __shared__ float Wl[128 * 32];
    __shared__ float Xl[8 * 128];
    const int tid = threadIdx.x;
    for (int i = tid; i < 128 * 32; i += 256) Wl[i] = W[i];

    const int row0 = blockIdx.x * 8;
    {
        int idx = tid * 4;
        int r = idx >> 7, c = idx & 127;
        if (row0 + r < n)
            *reinterpret_cast<float4*>(&Xl[idx]) =
                *reinterpret_cast<const float4*>(&X[(size_t)(row0 + r) * 128 + c]);
    }
    __syncthreads();

    const int r = tid >> 5, c = tid & 31;
    const int row = row0 + r;
    if (row >= n) return;

    float acc = 0.f;
#pragma unroll
    for (int k = 0; k < 128; ++k) acc += Xl[r * 128 + k] * Wl[k * 32 + c];
    H[(size_t)row * 32 + c] = acc;

    float vs = acc * a_s[c];
    float vd = acc * a_d[c];
#pragma unroll
    for (int o = 16; o; o >>= 1) { vs += __shfl_xor(vs, o, 32); vd += __shfl_xor(vd, o, 32); }
    if (c == 0) { Ss[row] = vs; Sd[row] = vd; }
}

__global__ __launch_bounds__(256) void k_feat2(
    const float* __restrict__ In, const float* __restrict__ W,
    const float* __restrict__ bias,
    const float* __restrict__ a_s, const float* __restrict__ a_d,
    float* __restrict__ H, float* __restrict__ Ss, float* __restrict__ Sd, int n)
{
    __shared__ float Wl[32 * 32];
    __shared__ float Xl[8 * 32];
    const int tid = threadIdx.x;
    for (int i = tid; i < 1024; i += 256) Wl[i] = W[i];

    const int r = tid >> 5, c = tid & 31;
    const int row = blockIdx.x * 8 + r;
    if (row < n) Xl[tid] = fmaxf(In[(size_t)row * 32 + c] + bias[c], 0.f);
    __syncthreads();
    if (row >= n) return;

    float acc = 0.f;
#pragma unroll
    for (int k = 0; k < 32; ++k) acc += Xl[r * 32 + k] * Wl[k * 32 + c];
    H[(size_t)row * 32 + c] = acc;

    float vs = acc * a_s[c];
    float vd = acc * a_d[c];
#pragma unroll
    for (int o = 16; o; o >>= 1) { vs += __shfl_xor(vs, o, 32); vd += __shfl_xor(vd, o, 32); }
    if (c == 0) { Ss[row] = vs; Sd[row] = vd; }
}

__global__ __launch_bounds__(256) void k_cls(
    const float* __restrict__ In, const float* __restrict__ W,
    const float* __restrict__ b_prev, const float* __restrict__ bc,
    float* __restrict__ Out, int n)
{
    __shared__ float Wl[32 * 32];
    __shared__ float Xl[8 * 32];
    const int tid = threadIdx.x;
    for (int i = tid; i < 1024; i += 256) Wl[i] = W[i];

    const int r = tid >> 5, c = tid & 31;
    const int row = blockIdx.x * 8 + r;
    if (row < n) Xl[tid] = fmaxf(In[(size_t)row * 32 + c] + b_prev[c], 0.f);
    __syncthreads();
    if (row >= n) return;

    float acc = bc[c];
#pragma unroll
    for (int k = 0; k < 32; ++k) acc += Xl[r * 32 + k] * Wl[k * 32 + c];
    Out[(size_t)row * 32 + c] = 1.f / (1.f + __expf(-acc));
}

// ---------------- bucketed CSR build ----------------
// Buckets of 256 consecutive dst nodes. ngroups = ceil(N/256) (must be <= 511).

#define NBH 256  // histogram blocks (persistent, 1 per CU)

// coarse bucket histogram: LDS-private per block, store partials (NO global atomics)
__global__ __launch_bounds__(256) void k_bhist(const int* __restrict__ edst, int E,
                                               int* __restrict__ hpart, int ngroups)
{
    __shared__ int h[512];
    const int tid = threadIdx.x;
    for (int i = tid; i < ngroups; i += 256) h[i] = 0;
    __syncthreads();
    const int nv = E >> 2;
    for (int i = blockIdx.x * 256 + tid; i < nv; i += NBH * 256) {
        int4 d = *reinterpret_cast<const int4*>(&edst[i << 2]);
        atomicAdd(&h[d.x >> 8], 1); atomicAdd(&h[d.y >> 8], 1);
        atomicAdd(&h[d.z >> 8], 1); atomicAdd(&h[d.w >> 8], 1);
    }
    if (blockIdx.x == 0 && tid < (E & 3))
        atomicAdd(&h[edst[(nv << 2) + tid] >> 8], 1);
    __syncthreads();
    // transposed partials: hpart[bucket * NBH + block]
    for (int i = tid; i < ngroups; i += 256) hpart[i * NBH + blockIdx.x] = h[i];
}

// single block: reduce partials, exclusive scan -> bstart; init bcur; off[N]=E+N
__global__ __launch_bounds__(512) void k_bscan(const int* __restrict__ hpart, int ngroups,
    int* __restrict__ bstart, int* __restrict__ bcur, int* __restrict__ off,
    int N, int E)
{
    __shared__ int sm[512];
    int t = threadIdx.x;
    int v = 0;
    if (t < ngroups) {
        const int4* row = reinterpret_cast<const int4*>(&hpart[t * NBH]);
#pragma unroll 4
        for (int b = 0; b < NBH / 4; ++b) { int4 x = row[b]; v += x.x + x.y + x.z + x.w; }
    }
    sm[t] = v; __syncthreads();
    for (int o = 1; o < 512; o <<= 1) {
        int x = sm[t];
        if (t >= o) x += sm[t - o];
        __syncthreads();
        sm[t] = x;
        __syncthreads();
    }
    if (t <= ngroups) {
        int ex = (t == 0) ? 0 : sm[t - 1];
        bstart[t] = ex;
        if (t < ngroups) bcur[t] = ex;
    }
    if (t == 0) off[N] = E + N;
}

// pass 1: partition packed records (dstlow<<24 | src) by dst>>8 into ebuf
#define CHUNK 4096
#define KPT 16

__global__ __launch_bounds__(256) void k_part(
    const int* __restrict__ esrc, const int* __restrict__ edst, int E,
    int* __restrict__ bcur, unsigned int* __restrict__ ebuf, int ngroups)
{
    __shared__ int hist[512];
    __shared__ int lofs[513];
    __shared__ int gbase[512];
    __shared__ unsigned int stage[CHUNK];
    const int tid = threadIdx.x;

    for (int c0 = blockIdx.x * CHUNK; c0 < E; c0 += gridDim.x * CHUNK) {
        const int cnt = min(CHUNK, E - c0);
        for (int i = tid; i < 512; i += 256) hist[i] = 0;
        __syncthreads();

        int bp[KPT];   // (b<<20) | (dstlow<<12) | pos   (pos < 4096)
#pragma unroll
        for (int k = 0; k < KPT; ++k) {
            int i = c0 + k * 256 + tid;
            bp[k] = -1;
            if (i < E) {
                int d = edst[i];
                int b = d >> 8;
                int pos = atomicAdd(&hist[b], 1);
                bp[k] = (b << 20) | ((d & 255) << 12) | pos;
            }
        }
        __syncthreads();

        if (tid < 64) {           // exclusive scan of hist[0..512) by one wave
            int base = tid * 8, v[8], s = 0;
#pragma unroll
            for (int k = 0; k < 8; ++k) { v[k] = hist[base + k]; s += v[k]; }
            int pre = s;
            for (int o = 1; o < 64; o <<= 1) {
                int t2 = __shfl_up(pre, o, 64);
                if (tid >= o) pre += t2;
            }
            pre -= s;
#pragma unroll
            for (int k = 0; k < 8; ++k) { lofs[base + k] = pre; pre += v[k]; }
            if (tid == 63) lofs[512] = pre;
        }
        __syncthreads();

        for (int b = tid; b < ngroups; b += 256)
            if (hist[b] > 0) gbase[b] = atomicAdd(&bcur[b], hist[b]);
        __syncthreads();

#pragma unroll
        for (int k = 0; k < KPT; ++k) {
            if (bp[k] >= 0) {
                int i = c0 + k * 256 + tid;
                int b = bp[k] >> 20, dl = (bp[k] >> 12) & 255, pos = bp[k] & 4095;
                stage[lofs[b] + pos] = ((unsigned)dl << 24) | (unsigned)esrc[i];
            }
        }
        __syncthreads();

        for (int i = tid; i < cnt; i += 256) {
            int b = 0;   // largest b with lofs[b] <= i  (lands on nonempty bucket)
            for (int step = 256; step; step >>= 1)
                if (b + step <= 512 && lofs[b + step] <= i) b += step;
            ebuf[(size_t)gbase[b] + (i - lofs[b])] = stage[i];
        }
        __syncthreads();
    }
}

// pass 2: one block per bucket. Count per-node degree in LDS, scan (+self-loop),
// write off[] and the sorted segment fully coalesced.
#define RCAP 11264  // 44KB

__global__ __launch_bounds__(256) void k_place2(
    const unsigned int* __restrict__ ebuf, const int* __restrict__ bstart,
    int* __restrict__ off, int* __restrict__ esorted, int* __restrict__ gcur, int N)
{
    __shared__ int R[RCAP];
    __shared__ int cnt[256];
    __shared__ int lcur[256];
    __shared__ int sm[256];
    const int g = blockIdx.x, tid = threadIdx.x;
    const int d0 = g << 8, d1 = min(d0 + 256, N);
    const int nd = d1 - d0;
    const int eb = bstart[g];
    const int ecnt = bstart[g + 1] - eb;
    const int base = eb + d0;               // segment start incl. preceding self-loops
    const int len = ecnt + nd;

    cnt[tid] = 0;
    __syncthreads();
    for (int i = tid; i < ecnt; i += 256)
        atomicAdd(&cnt[ebuf[eb + i] >> 24], 1);
    __syncthreads();

    // inclusive scan of (cnt[t]+1)
    int v = (tid < nd) ? cnt[tid] + 1 : 0;
    sm[tid] = v; __syncthreads();
    for (int o = 1; o < 256; o <<= 1) {
        int x = sm[tid];
        if (tid >= o) x += sm[tid - o];
        __syncthreads();
        sm[tid] = x;
        __syncthreads();
    }
    int lo = sm[tid] - v;                    // exclusive

    if (len <= RCAP) {
        if (tid < nd) {
            off[d0 + tid] = base + lo;
            R[lo] = d0 + tid;                // self-loop at segment head
            lcur[tid] = lo + 1;
        }
        __syncthreads();
        for (int i = tid; i < ecnt; i += 256) {
            unsigned int w = ebuf[eb + i];
            int pos = atomicAdd(&lcur[w >> 24], 1);
            R[pos] = (int)(w & 0xffffffu);
        }
        __syncthreads();
        for (int i = tid; i < len; i += 256) esorted[base + i] = R[i];
    } else {                                 // overflow fallback (statistically never)
        if (tid < nd) {
            off[d0 + tid] = base + lo;
            esorted[base + lo] = d0 + tid;
            gcur[d0 + tid] = base + lo + 1;
        }
        __syncthreads();
        for (int i = tid; i < ecnt; i += 256) {
            unsigned int w = ebuf[eb + i];
            esorted[atomicAdd(&gcur[d0 + (int)(w >> 24)], 1)] = (int)(w & 0xffffffu);
        }
    }
}

// ---------------- global max of Ss (two stage) ----------------

__global__ __launch_bounds__(256) void k_max1(const float* __restrict__ Ss, int n,
                                              float* __restrict__ part)
{
    float m = -INFINITY;
    for (int i = blockIdx.x * 256 + threadIdx.x; i < n; i += gridDim.x * 256)
        m = fmaxf(m, Ss[i]);
    __shared__ float sm[256];
    sm[threadIdx.x] = m; __syncthreads();
    for (int o = 128; o; o >>= 1) {
        if (threadIdx.x < o) sm[threadIdx.x] = fmaxf(sm[threadIdx.x], sm[threadIdx.x + o]);
        __syncthreads();
    }
    if (threadIdx.x == 0) part[blockIdx.x] = sm[0];
}

__global__ void k_max2(const float* __restrict__ part, int nb, float* __restrict__ out)
{
    float m = -INFINITY;
    for (int i = threadIdx.x; i < nb; i += 64) m = fmaxf(m, part[i]);
    for (int o = 32; o; o >>= 1) m = fmaxf(m, __shfl_xor(m, o, 64));
    if (threadIdx.x == 0) out[0] = m;
}

// ---------------- fused GAT aggregation ----------------

__global__ __launch_bounds__(256) void k_gat(
    const int* __restrict__ off, const int* __restrict__ esorted,
    const float* __restrict__ Ss, const float* __restrict__ Sd,
    const float* __restrict__ maxSs, const float* __restrict__ H,
    float* __restrict__ out, int n)
{
    int g = blockIdx.x * 8 + (threadIdx.x >> 5);
    int lane = threadIdx.x & 31;
    if (g >= n) return;

    float sd = Sd[g];
    float ub = lrelu(maxSs[0] + sd);   // >= true segment max (lrelu monotone)
    int j = off[g], j1 = off[g + 1];

    float z = 0.f, acc = 0.f;
    for (; j + 3 < j1; j += 4) {
        int s0 = esorted[j], s1 = esorted[j + 1], s2 = esorted[j + 2], s3 = esorted[j + 3];
        float w0 = __expf(lrelu(Ss[s0] + sd) - ub);
        float w1 = __expf(lrelu(Ss[s1] + sd) - ub);
        float w2 = __expf(lrelu(Ss[s2] + sd) - ub);
        float w3 = __expf(lrelu(Ss[s3] + sd) - ub);
        float h0 = H[(size_t)s0 * 32 + lane];
        float h1 = H[(size_t)s1 * 32 + lane];
        float h2 = H[(size_t)s2 * 32 + lane];
        float h3 = H[(size_t)s3 * 32 + lane];
        z += (w0 + w1) + (w2 + w3);
        acc += w0 * h0 + w1 * h1 + w2 * h2 + w3 * h3;
    }
    for (; j < j1; ++j) {
        int s = esorted[j];
        float w = __expf(lrelu(Ss[s] + sd) - ub);
        z += w;
        acc += w * H[(size_t)s * 32 + lane];
    }
    out[(size_t)g * 32 + lane] = acc / (z + 1e-16f);
}

// ---------------- launch ----------------

extern "C" void kernel_launch(void* const* d_in, const int* in_sizes, int n_in,
                              void* d_out, int out_size, void* d_ws, size_t ws_size,
                              hipStream_t stream)
{
    const float* x   = (const float*)d_in[0];
    const int*   ei  = (const int*)d_in[1];
    const float* W1  = (const float*)d_in[2];
    const float* as1 = (const float*)d_in[3];
    const float* ad1 = (const float*)d_in[4];
    const float* b1  = (const float*)d_in[5];
    const float* W2  = (const float*)d_in[6];
    const float* as2 = (const float*)d_in[7];
    const float* ad2 = (const float*)d_in[8];
    const float* b2  = (const float*)d_in[9];
    const float* Wc  = (const float*)d_in[10];
    const float* bc  = (const float*)d_in[11];

    const int N = in_sizes[0] / 128;
    const int E = in_sizes[1] / 2;
    const int* esrc = ei;
    const int* edst = ei + E;
    const int ngroups = (N + 255) >> 8;      // must be <= 511

    // workspace carve-up
    char* p = (char*)d_ws;
    float* H     = (float*)p; p += (size_t)N * 32 * 4;   // 12.8 MB  (ebuf aliases H)
    float* AGG   = (float*)p; p += (size_t)N * 32 * 4;   // 12.8 MB
    float* Ss    = (float*)p; p += (size_t)N * 4;
    float* Sd    = (float*)p; p += (size_t)N * 4;
    float* MSS   = (float*)p; p += 256;
    int*   off   = (int*)p;   p += (size_t)(N + 1) * 4;
    int*   gcur  = (int*)p;   p += (size_t)N * 4;        // overflow fallback only
    int*   part  = (int*)p;   p += 256 * 4;              // max partials
    int*   hpart = (int*)p;   p += 512 * NBH * 4;        // 512 KB histogram partials
    int*   bstart= (int*)p;   p += 513 * 4;
    int*   bcur  = (int*)p;   p += 512 * 4;
    int*   esort = (int*)p;   p += (size_t)(E + N) * 4;  // 13.2 MB

    unsigned int* ebuf = (unsigned int*)H;               // 12.8 MB alias (build only)

    const dim3 blk(256);
    const int nb_rows = (N + 7) / 8;

    // ---- bucketed CSR build (by dst), shared by both layers ----
    k_bhist<<<NBH, blk, 0, stream>>>(edst, E, hpart, ngroups);
    k_bscan<<<1, 512, 0, stream>>>(hpart, ngroups, bstart, bcur, off, N, E);
    k_part<<<768, blk, 0, stream>>>(esrc, edst, E, bcur, ebuf, ngroups);
    k_place2<<<ngroups, blk, 0, stream>>>(ebuf, bstart, off, esort, gcur, N);

    // ---- Layer 1 ----  (feat1 overwrites H => ebuf dead from here on)
    k_feat1<<<nb_rows, blk, 0, stream>>>(x, W1, as1, ad1, H, Ss, Sd, N);
    k_max1<<<128, blk, 0, stream>>>(Ss, N, (float*)part);
    k_max2<<<1, 64, 0, stream>>>((float*)part, 128, MSS);
    k_gat<<<(N + 7) / 8, blk, 0, stream>>>(off, esort, Ss, Sd, MSS, H, AGG, N);

    // ---- Layer 2 ----
    k_feat2<<<nb_rows, blk, 0, stream>>>(AGG, W2, b1, as2, ad2, H, Ss, Sd, N);
    k_max1<<<128, blk, 0, stream>>>(Ss, N, (float*)part);
    k_max2<<<1, 64, 0, stream>>>((float*)part, 128, MSS);
    k_gat<<<(N + 7) / 8, blk, 0, stream>>>(off, esort, Ss, Sd, MSS, H, AGG, N);

    // ---- Classifier ----
    k_cls<<<nb_rows, blk, 0, stream>>>(AGG, Wc, b2, bc, (float*)d_out, N);
}